// Round 1
// baseline (308.833 us; speedup 1.0000x reference)
//
#include <hip/hip_runtime.h>
#include <math.h>

#define Hh 512
#define Ww 512
#define Bb 8
#define CI 32
#define CO 32
#define HM 16   // kx modes kept
#define KYp 32  // packed ky modes (0..15 and 496..511)

static constexpr float TWO_PI = 6.28318530717958647692f;

// workspace layout (float offsets)
#define A_OFF  0u         // [B*CI][512][16][2]  = 4,194,304 floats
#define F_OFF  4194304u   // [B*CI][32][16][2]   =   262,144 floats
#define G_OFF  4456448u   // [B*CO][32][16][2]   =   262,144 floats
#define g_OFF  4718592u   // [B*CO][512][16][2]  = 4,194,304 floats
// total 8,912,896 floats = 35,651,584 bytes of d_ws

// ---------------- Stage 1: per-row DFT over w, 16 bins -----------------
__global__ __launch_bounds__(256) void s1_kernel(const float* __restrict__ x,
                                                 float* __restrict__ A) {
  __shared__ float xs[16 * 516];  // 16 rows, pad 4 -> conflict-free reads
  const int tid = threadIdx.x;
  const int blk = blockIdx.x;
  const int tile = blk & 31;   // 32 tiles of 16 rows
  const int bi = blk >> 5;     // b*CI + i
  const float* xbase = x + (size_t)bi * (Hh * Ww) + (size_t)tile * 16 * Ww;
  #pragma unroll
  for (int j = 0; j < 8; ++j) {
    int idx = tid + j * 256;        // float4 index 0..2047
    int r = idx >> 7;
    int c4 = (idx & 127) << 2;
    float4 v = *(const float4*)(xbase + (size_t)r * Ww + c4);
    *(float4*)(&xs[r * 516 + c4]) = v;
  }
  __syncthreads();
  const int r = tid >> 4;
  const int kx = tid & 15;
  float sd, cd;
  sincosf(TWO_PI * (float)kx / 512.0f, &sd, &cd);
  float c = 1.0f, s = 0.0f, sr = 0.0f, si = 0.0f;
  const float* xr = &xs[r * 516];
  #pragma unroll 8
  for (int w = 0; w < 512; ++w) {
    float xv = xr[w];
    sr = fmaf(xv, c, sr);
    si = fmaf(xv, s, si);
    float cn = c * cd - s * sd;      // rotate by e^{i*2pi*kx/512}
    s = fmaf(c, sd, s * cd);
    c = cn;
  }
  // A = sum x * e^{-i theta} = (sr, -si)
  size_t o = ((size_t)bi * Hh + tile * 16 + r) * (HM * 2) + kx * 2;
  *(float2*)(A + o) = make_float2(sr, -si);
}

// ---------------- Stage 2: DFT over h, 32 bins (ky 0..15, 496..511) ----
__global__ __launch_bounds__(512) void s2_kernel(const float* __restrict__ A,
                                                 float* __restrict__ F) {
  __shared__ float As[Hh * 32];   // 64 KB: full A image of one (b,i)
  __shared__ float ct[512];
  __shared__ float st[512];
  const int tid = threadIdx.x;
  const int bi = blockIdx.x;
  {
    float ang = TWO_PI * (float)tid / 512.0f;
    ct[tid] = cosf(ang);
    st[tid] = sinf(ang);
  }
  const float4* Ab = (const float4*)(A + (size_t)bi * (Hh * 32));
  float4* Asv = (float4*)As;
  #pragma unroll
  for (int j = 0; j < 8; ++j) Asv[tid + j * 512] = Ab[tid + j * 512];
  __syncthreads();
  const int kyp = tid >> 4;                       // 0..31
  const int kx = tid & 15;
  const int ky = (kyp < 16) ? kyp : (kyp + 480);  // 0..15 or 496..511
  float fr = 0.f, fi = 0.f;
  int t = 0;
  for (int h = 0; h < 512; ++h) {
    float2 a = *(const float2*)&As[h * 32 + kx * 2];
    float cc = ct[t], ss = st[t];
    // (ar + i ai) * (cc - i ss)
    fr = fmaf(a.x, cc, fr); fr = fmaf(a.y, ss, fr);
    fi = fmaf(a.y, cc, fi); fi = fmaf(-a.x, ss, fi);
    t = (t + ky) & 511;
  }
  size_t o = ((size_t)bi * KYp + kyp) * (HM * 2) + kx * 2;
  *(float2*)(F + o) = make_float2(fr, fi);
}

// ---------------- Stage 3: complex channel mix -------------------------
__global__ __launch_bounds__(512) void mix_kernel(const float* __restrict__ F,
    const float* __restrict__ w1r, const float* __restrict__ w1i,
    const float* __restrict__ w2r, const float* __restrict__ w2i,
    float* __restrict__ G) {
  const int tid = threadIdx.x;
  const int b = blockIdx.x >> 5;   // blockIdx = b*CO + o
  const int o = blockIdx.x & 31;
  const int kyp = tid >> 4;
  const int kx = tid & 15;
  const bool top = kyp < 16;
  const int m = top ? kyp : (kyp - 16);
  const float* wr = top ? w1r : w2r;
  const float* wi = top ? w1i : w2i;
  float gr = 0.f, gi = 0.f;
  for (int i = 0; i < CI; ++i) {
    float2 f = *(const float2*)&F[(((size_t)b * CI + i) * KYp + kyp) * (HM * 2) + kx * 2];
    size_t wo = (((size_t)i * CO + o) * HM + m) * HM + kx;
    float wrv = wr[wo], wiv = wi[wo];
    gr = fmaf(f.x, wrv, gr); gr = fmaf(-f.y, wiv, gr);
    gi = fmaf(f.x, wiv, gi); gi = fmaf(f.y, wrv, gi);
  }
  size_t go = ((size_t)blockIdx.x) * (KYp * HM * 2) + (kyp * HM + kx) * 2;
  *(float2*)(G + go) = make_float2(gr, gi);
}

// ---------------- Stage 4: inverse DFT over ky -> 512 rows -------------
__global__ __launch_bounds__(256) void t1_kernel(const float* __restrict__ G,
                                                 float* __restrict__ gws) {
  __shared__ float Gs[KYp * HM * 2];  // 4 KB
  __shared__ float ct[512];
  __shared__ float st[512];
  const int tid = threadIdx.x;
  const int blk = blockIdx.x;
  const int tile = blk & 31;
  const int bo = blk >> 5;
  #pragma unroll
  for (int j = 0; j < 2; ++j) {
    int t = tid + j * 256;
    float ang = TWO_PI * (float)t / 512.0f;
    ct[t] = cosf(ang);
    st[t] = sinf(ang);
  }
  ((float4*)Gs)[tid] = ((const float4*)(G + (size_t)bo * (KYp * HM * 2)))[tid];
  __syncthreads();
  const int r = tid >> 4;
  const int kx = tid & 15;
  const int h = tile * 16 + r;
  float gr = 0.f, gi = 0.f;
  #pragma unroll
  for (int kyp = 0; kyp < 32; ++kyp) {
    const int ky = (kyp < 16) ? kyp : (kyp + 480);
    const int t = (ky * h) & 511;
    float cc = ct[t], ss = st[t];
    float2 Gv = *(const float2*)&Gs[(kyp * HM + kx) * 2];
    // (Gr + i Gi) * (cc + i ss)
    gr = fmaf(Gv.x, cc, gr); gr = fmaf(-Gv.y, ss, gr);
    gi = fmaf(Gv.x, ss, gi); gi = fmaf(Gv.y, cc, gi);
  }
  size_t o = ((size_t)bo * Hh + h) * (HM * 2) + kx * 2;
  *(float2*)(gws + o) = make_float2(gr, gi);
}

// ---------------- Stage 5: inverse DFT over kx -> 512 cols, +bias ------
__global__ __launch_bounds__(256) void t2_kernel(const float* __restrict__ gws,
                                                 const float* __restrict__ bias,
                                                 float* __restrict__ y) {
  const int tid = threadIdx.x;
  const int blk = blockIdx.x;
  const int q = blk & 3;       // row quarter (128 rows)
  const int bo = blk >> 2;     // b*CO + o
  const int o = bo & 31;
  const float bv = bias[o];
  const float inv = 1.0f / 262144.0f;  // 1/(H*W)
  const int w0 = tid;          // columns w0 and w0+256
  float C[15], S[15];
  #pragma unroll
  for (int k = 0; k < 15; ++k) {
    int t = ((k + 1) * w0) & 511;
    float ang = TWO_PI * (float)t / 512.0f;
    float sv, cv;
    sincosf(ang, &sv, &cv);
    C[k] = 2.0f * cv;   // fold the hermitian x2 into the twiddle
    S[k] = 2.0f * sv;
  }
  const float* grow = gws + ((size_t)bo * Hh + q * 128) * (HM * 2);
  float* yrow = y + ((size_t)bo * Hh + q * 128) * Ww;
  for (int r = 0; r < 128; ++r) {
    float qa[32];
    const float4* gp = (const float4*)(grow + r * (HM * 2));
    #pragma unroll
    for (int j = 0; j < 8; ++j) ((float4*)qa)[j] = gp[j];
    // even/odd-k split: col w0 gets E+O, col w0+256 gets E-O (cos(th+k*pi))
    float E = qa[0];       // DC: real part only (pocketfft c2r semantics)
    float O = 0.f, E2 = 0.f, O2 = 0.f;
    #pragma unroll
    for (int k = 1; k <= 15; ++k) {
      float tv = fmaf(-qa[2 * k + 1], S[k - 1], qa[2 * k] * C[k - 1]);
      if (k & 1) { if (k & 2) O2 += tv; else O += tv; }
      else       { if (k & 2) E2 += tv; else E += tv; }
    }
    float Ee = E + E2, Oo = O + O2;
    yrow[r * Ww + w0]       = fmaf(inv, Ee + Oo, bv);
    yrow[r * Ww + w0 + 256] = fmaf(inv, Ee - Oo, bv);
  }
}

extern "C" void kernel_launch(void* const* d_in, const int* in_sizes, int n_in,
                              void* d_out, int out_size, void* d_ws, size_t ws_size,
                              hipStream_t stream) {
  const float* x    = (const float*)d_in[0];
  const float* w1r  = (const float*)d_in[1];
  const float* w1i  = (const float*)d_in[2];
  const float* w2r  = (const float*)d_in[3];
  const float* w2i  = (const float*)d_in[4];
  const float* bias = (const float*)d_in[5];
  float* y  = (float*)d_out;
  float* ws = (float*)d_ws;
  float* A  = ws + A_OFF;
  float* F  = ws + F_OFF;
  float* G  = ws + G_OFF;
  float* g  = ws + g_OFF;

  hipLaunchKernelGGL(s1_kernel,  dim3(Bb * CI * 32), dim3(256), 0, stream, x, A);
  hipLaunchKernelGGL(s2_kernel,  dim3(Bb * CI),      dim3(512), 0, stream, A, F);
  hipLaunchKernelGGL(mix_kernel, dim3(Bb * CO),      dim3(512), 0, stream, F,
                     w1r, w1i, w2r, w2i, G);
  hipLaunchKernelGGL(t1_kernel,  dim3(Bb * CO * 32), dim3(256), 0, stream, G, g);
  hipLaunchKernelGGL(t2_kernel,  dim3(Bb * CO * 4),  dim3(256), 0, stream, g, bias, y);
}

// Round 2
// 233.277 us; speedup vs baseline: 1.3239x; 1.3239x over previous
//
#include <hip/hip_runtime.h>
#include <math.h>

#define Hh 512
#define Ww 512
#define Bb 8
#define CI 32
#define CO 32
#define HM 16   // kx modes kept
#define KYp 32  // packed ky modes (0..15 and 496..511)

static constexpr float TWO_PI = 6.28318530717958647692f;

// workspace layout (float offsets)
#define A_OFF  0u         // [B*CI][512][16][2]  = 4,194,304 floats
#define F_OFF  4194304u   // [B*CI][32][16][2]   =   262,144 floats
#define G_OFF  4456448u   // [B*CO][32][16][2]   =   262,144 floats
#define g_OFF  4718592u   // [B*CO][512][16][2]  = 4,194,304 floats
// E (bf16 DFT fragments, 32 KB) lives at the START of the g region:
// s1 reads it, t1 later overwrites it — by then E is dead. No extra ws.

using short8 = __attribute__((ext_vector_type(8))) short;
using f32x16 = __attribute__((ext_vector_type(16))) float;

__device__ inline unsigned short bf16_rn(float f) {
  unsigned u = __float_as_uint(f);
  u += 0x7FFFu + ((u >> 16) & 1u);
  return (unsigned short)(u >> 16);
}

// --------- E init: DFT matrix in MFMA B-fragment order [s][lane][8] ----
// k = 16*s + 8*(lane>>5) + j ; col = lane&31 ; kx = col>>1
// col even: cos(2pi*kx*k/512), col odd: -sin(...)
__global__ __launch_bounds__(256) void e_init_kernel(float* __restrict__ Ef) {
  unsigned short* E = (unsigned short*)Ef;
  int idx = blockIdx.x * 256 + threadIdx.x;   // 0..16383
  int s = idx >> 9;
  int l = (idx >> 3) & 63;
  int j = idx & 7;
  int k = 16 * s + 8 * (l >> 5) + j;
  int col = l & 31;
  int kx = col >> 1;
  int t = (kx * k) & 511;
  float ang = TWO_PI * (float)t / 512.0f;
  float sv, cv;
  sincosf(ang, &sv, &cv);
  float val = (col & 1) ? -sv : cv;
  E[idx] = bf16_rn(val);
}

// ---------------- Stage 1: MFMA GEMM  A = X * E ------------------------
// X: [131072 x 512] fp32 (split hi/lo bf16), E: [512 x 32] bf16
// block = 256 thr = 4 waves; each wave: 32 rows x 32 cols, K=512
__global__ __launch_bounds__(256) void s1_kernel(const float* __restrict__ x,
                                                 const float* __restrict__ Ef,
                                                 float* __restrict__ A) {
  __shared__ alignas(16) short Elds[16384];   // 32 KB
  const int tid = threadIdx.x;
  // stage E -> LDS (linear, coalesced)
  {
    const float4* Eg = (const float4*)Ef;
    float4* El = (float4*)Elds;
    #pragma unroll
    for (int j = 0; j < 8; ++j) El[tid + j * 256] = Eg[tid + j * 256];
  }
  __syncthreads();

  const int l = tid & 63;
  const int wid = tid >> 6;
  const int row = blockIdx.x * 128 + wid * 32 + (l & 31);
  const float* ap = x + (size_t)row * 512 + ((l >> 5) * 8);
  const short* ebase = Elds + l * 8;

  f32x16 acc = {0.f,0.f,0.f,0.f,0.f,0.f,0.f,0.f,0.f,0.f,0.f,0.f,0.f,0.f,0.f,0.f};

  #pragma unroll 8
  for (int s = 0; s < 32; ++s) {
    float4 v0 = *(const float4*)(ap + s * 16);
    float4 v1 = *(const float4*)(ap + s * 16 + 4);
    short8 hi, lo;
    #pragma unroll
    for (int j = 0; j < 8; ++j) {
      float f = (j < 4) ? ((const float*)&v0)[j] : ((const float*)&v1)[j - 4];
      unsigned u = __float_as_uint(f);
      float fl = f - __uint_as_float(u & 0xFFFF0000u);   // exact
      hi[j] = (short)(u >> 16);                          // exact bf16 (trunc)
      lo[j] = (short)(__float_as_uint(fl) >> 16);        // err <= 2^-17 |f|
    }
    short8 e = *(const short8*)(ebase + s * 512);
    acc = __builtin_amdgcn_mfma_f32_32x32x16_bf16(hi, e, acc, 0, 0, 0);
    acc = __builtin_amdgcn_mfma_f32_32x32x16_bf16(lo, e, acc, 0, 0, 0);
  }

  // C layout: col = lane&31, row = (reg&3) + 8*(reg>>2) + 4*(lane>>5)
  const int col = l & 31;
  const int rq = (l >> 5) * 4;
  const int rb = blockIdx.x * 128 + wid * 32;
  #pragma unroll
  for (int r = 0; r < 16; ++r) {
    int rowt = (r & 3) + 8 * (r >> 2) + rq;
    A[(size_t)(rb + rowt) * 32 + col] = acc[r];
  }
}

// ---------------- Stage 2: DFT over h, 32 bins (ky 0..15, 496..511) ----
__global__ __launch_bounds__(512) void s2_kernel(const float* __restrict__ A,
                                                 float* __restrict__ F) {
  __shared__ float As[Hh * 32];   // 64 KB: full A image of one (b,i)
  __shared__ float ct[512];
  __shared__ float st[512];
  const int tid = threadIdx.x;
  const int bi = blockIdx.x;
  {
    float ang = TWO_PI * (float)tid / 512.0f;
    ct[tid] = cosf(ang);
    st[tid] = sinf(ang);
  }
  const float4* Ab = (const float4*)(A + (size_t)bi * (Hh * 32));
  float4* Asv = (float4*)As;
  #pragma unroll
  for (int j = 0; j < 8; ++j) Asv[tid + j * 512] = Ab[tid + j * 512];
  __syncthreads();
  const int kyp = tid >> 4;                       // 0..31
  const int kx = tid & 15;
  const int ky = (kyp < 16) ? kyp : (kyp + 480);  // 0..15 or 496..511
  float fr = 0.f, fi = 0.f;
  int t = 0;
  for (int h = 0; h < 512; ++h) {
    float2 a = *(const float2*)&As[h * 32 + kx * 2];
    float cc = ct[t], ss = st[t];
    // (ar + i ai) * (cc - i ss)
    fr = fmaf(a.x, cc, fr); fr = fmaf(a.y, ss, fr);
    fi = fmaf(a.y, cc, fi); fi = fmaf(-a.x, ss, fi);
    t = (t + ky) & 511;
  }
  size_t o = ((size_t)bi * KYp + kyp) * (HM * 2) + kx * 2;
  *(float2*)(F + o) = make_float2(fr, fi);
}

// ---------------- Stage 3: complex channel mix -------------------------
__global__ __launch_bounds__(512) void mix_kernel(const float* __restrict__ F,
    const float* __restrict__ w1r, const float* __restrict__ w1i,
    const float* __restrict__ w2r, const float* __restrict__ w2i,
    float* __restrict__ G) {
  const int tid = threadIdx.x;
  const int b = blockIdx.x >> 5;   // blockIdx = b*CO + o
  const int o = blockIdx.x & 31;
  const int kyp = tid >> 4;
  const int kx = tid & 15;
  const bool top = kyp < 16;
  const int m = top ? kyp : (kyp - 16);
  const float* wr = top ? w1r : w2r;
  const float* wi = top ? w1i : w2i;
  float gr = 0.f, gi = 0.f;
  for (int i = 0; i < CI; ++i) {
    float2 f = *(const float2*)&F[(((size_t)b * CI + i) * KYp + kyp) * (HM * 2) + kx * 2];
    size_t wo = (((size_t)i * CO + o) * HM + m) * HM + kx;
    float wrv = wr[wo], wiv = wi[wo];
    gr = fmaf(f.x, wrv, gr); gr = fmaf(-f.y, wiv, gr);
    gi = fmaf(f.x, wiv, gi); gi = fmaf(f.y, wrv, gi);
  }
  size_t go = ((size_t)blockIdx.x) * (KYp * HM * 2) + (kyp * HM + kx) * 2;
  *(float2*)(G + go) = make_float2(gr, gi);
}

// ---------------- Stage 4: inverse DFT over ky -> 512 rows -------------
__global__ __launch_bounds__(256) void t1_kernel(const float* __restrict__ G,
                                                 float* __restrict__ gws) {
  __shared__ float Gs[KYp * HM * 2];  // 4 KB
  __shared__ float ct[512];
  __shared__ float st[512];
  const int tid = threadIdx.x;
  const int blk = blockIdx.x;
  const int tile = blk & 31;
  const int bo = blk >> 5;
  #pragma unroll
  for (int j = 0; j < 2; ++j) {
    int t = tid + j * 256;
    float ang = TWO_PI * (float)t / 512.0f;
    ct[t] = cosf(ang);
    st[t] = sinf(ang);
  }
  ((float4*)Gs)[tid] = ((const float4*)(G + (size_t)bo * (KYp * HM * 2)))[tid];
  __syncthreads();
  const int r = tid >> 4;
  const int kx = tid & 15;
  const int h = tile * 16 + r;
  float gr = 0.f, gi = 0.f;
  #pragma unroll
  for (int kyp = 0; kyp < 32; ++kyp) {
    const int ky = (kyp < 16) ? kyp : (kyp + 480);
    const int t = (ky * h) & 511;
    float cc = ct[t], ss = st[t];
    float2 Gv = *(const float2*)&Gs[(kyp * HM + kx) * 2];
    // (Gr + i Gi) * (cc + i ss)
    gr = fmaf(Gv.x, cc, gr); gr = fmaf(-Gv.y, ss, gr);
    gi = fmaf(Gv.x, ss, gi); gi = fmaf(Gv.y, cc, gi);
  }
  size_t o = ((size_t)bo * Hh + h) * (HM * 2) + kx * 2;
  *(float2*)(gws + o) = make_float2(gr, gi);
}

// ---------------- Stage 5: inverse DFT over kx -> 512 cols, +bias ------
__global__ __launch_bounds__(256) void t2_kernel(const float* __restrict__ gws,
                                                 const float* __restrict__ bias,
                                                 float* __restrict__ y) {
  const int tid = threadIdx.x;
  const int blk = blockIdx.x;
  const int q = blk & 3;       // row quarter (128 rows)
  const int bo = blk >> 2;     // b*CO + o
  const int o = bo & 31;
  const float bv = bias[o];
  const float inv = 1.0f / 262144.0f;  // 1/(H*W)
  const int w0 = tid;          // columns w0 and w0+256
  float C[15], S[15];
  #pragma unroll
  for (int k = 0; k < 15; ++k) {
    int t = ((k + 1) * w0) & 511;
    float ang = TWO_PI * (float)t / 512.0f;
    float sv, cv;
    sincosf(ang, &sv, &cv);
    C[k] = 2.0f * cv;   // fold the hermitian x2 into the twiddle
    S[k] = 2.0f * sv;
  }
  const float* grow = gws + ((size_t)bo * Hh + q * 128) * (HM * 2);
  float* yrow = y + ((size_t)bo * Hh + q * 128) * Ww;
  for (int r = 0; r < 128; ++r) {
    float qa[32];
    const float4* gp = (const float4*)(grow + r * (HM * 2));
    #pragma unroll
    for (int j = 0; j < 8; ++j) ((float4*)qa)[j] = gp[j];
    // even/odd-k split: col w0 gets E+O, col w0+256 gets E-O (cos(th+k*pi))
    float E = qa[0];       // DC: real part only (pocketfft c2r semantics)
    float O = 0.f, E2 = 0.f, O2 = 0.f;
    #pragma unroll
    for (int k = 1; k <= 15; ++k) {
      float tv = fmaf(-qa[2 * k + 1], S[k - 1], qa[2 * k] * C[k - 1]);
      if (k & 1) { if (k & 2) O2 += tv; else O += tv; }
      else       { if (k & 2) E2 += tv; else E += tv; }
    }
    float Ee = E + E2, Oo = O + O2;
    yrow[r * Ww + w0]       = fmaf(inv, Ee + Oo, bv);
    yrow[r * Ww + w0 + 256] = fmaf(inv, Ee - Oo, bv);
  }
}

extern "C" void kernel_launch(void* const* d_in, const int* in_sizes, int n_in,
                              void* d_out, int out_size, void* d_ws, size_t ws_size,
                              hipStream_t stream) {
  const float* x    = (const float*)d_in[0];
  const float* w1r  = (const float*)d_in[1];
  const float* w1i  = (const float*)d_in[2];
  const float* w2r  = (const float*)d_in[3];
  const float* w2i  = (const float*)d_in[4];
  const float* bias = (const float*)d_in[5];
  float* y  = (float*)d_out;
  float* ws = (float*)d_ws;
  float* A  = ws + A_OFF;
  float* F  = ws + F_OFF;
  float* G  = ws + G_OFF;
  float* g  = ws + g_OFF;
  float* E  = ws + g_OFF;   // 32 KB, dead before t1 writes g

  hipLaunchKernelGGL(e_init_kernel, dim3(64),           dim3(256), 0, stream, E);
  hipLaunchKernelGGL(s1_kernel,  dim3(Bb * CI * 512 / 128), dim3(256), 0, stream, x, E, A);
  hipLaunchKernelGGL(s2_kernel,  dim3(Bb * CI),      dim3(512), 0, stream, A, F);
  hipLaunchKernelGGL(mix_kernel, dim3(Bb * CO),      dim3(512), 0, stream, F,
                     w1r, w1i, w2r, w2i, G);
  hipLaunchKernelGGL(t1_kernel,  dim3(Bb * CO * 32), dim3(256), 0, stream, G, g);
  hipLaunchKernelGGL(t2_kernel,  dim3(Bb * CO * 4),  dim3(256), 0, stream, g, bias, y);
}

// Round 3
// 228.054 us; speedup vs baseline: 1.3542x; 1.0229x over previous
//
#include <hip/hip_runtime.h>
#include <math.h>

#define Hh 512
#define Ww 512
#define Bb 8
#define CI 32
#define CO 32
#define HM 16   // kx modes kept
#define KYp 32  // packed ky modes (0..15 and 496..511)

static constexpr float TWO_PI = 6.28318530717958647692f;

// workspace layout (float offsets)
#define A_OFF  0u         // [B*CI][512][16][2]  = 4,194,304 floats
#define F_OFF  4194304u   // [B*CI][32][16][2]   =   262,144 floats
#define G_OFF  4456448u   // [B*CO][32][16][2]   =   262,144 floats
#define g_OFF  4718592u   // [B*CO][512][16][2]  = 4,194,304 floats
// E (bf16 DFT fragments, 32 KB) lives at the START of the g region:
// s1 reads it, t1 later overwrites it — by then E is dead. No extra ws.

using short8 = __attribute__((ext_vector_type(8))) short;
using f32x16 = __attribute__((ext_vector_type(16))) float;

__device__ inline unsigned short bf16_rn(float f) {
  unsigned u = __float_as_uint(f);
  u += 0x7FFFu + ((u >> 16) & 1u);
  return (unsigned short)(u >> 16);
}

// --------- E init: DFT matrix in MFMA B-fragment order [s][lane][8] ----
// k = 16*s + 8*(lane>>5) + j ; col = lane&31 ; kx = col>>1
// col even: cos(2pi*kx*k/512), col odd: -sin(...)
__global__ __launch_bounds__(256) void e_init_kernel(float* __restrict__ Ef) {
  unsigned short* E = (unsigned short*)Ef;
  int idx = blockIdx.x * 256 + threadIdx.x;   // 0..16383
  int s = idx >> 9;
  int l = (idx >> 3) & 63;
  int j = idx & 7;
  int k = 16 * s + 8 * (l >> 5) + j;
  int col = l & 31;
  int kx = col >> 1;
  int t = (kx * k) & 511;
  float ang = TWO_PI * (float)t / 512.0f;
  float sv, cv;
  sincosf(ang, &sv, &cv);
  float val = (col & 1) ? -sv : cv;
  E[idx] = bf16_rn(val);
}

// ---------------- Stage 1: MFMA GEMM  A = X * E ------------------------
// X: [131072 x 512] fp32 (split hi/lo bf16), E: [512 x 32] bf16
// block = 256 thr = 4 waves; each wave: 32 rows x 32 cols, K=512
// Coalesced global->reg, convert, ds_write fragment-order (XOR-swizzled),
// ds_read_b128 -> MFMA. Next tile's loads issued before the barrier (T14).
__global__ __launch_bounds__(256) void s1_kernel(const float* __restrict__ x,
                                                 const float* __restrict__ Ef,
                                                 float* __restrict__ A) {
  __shared__ alignas(16) short Eld[16384];  // 32 KB  [s 0..31][lane][8]
  __shared__ alignas(16) short Th[8192];    // 16 KB  hi  [w][s][lane^2s][8]
  __shared__ alignas(16) short Tl[8192];    // 16 KB  lo
  const int tid = threadIdx.x;
  // stage full E (32 KB) -> LDS, coalesced
  {
    const float4* Eg = (const float4*)Ef;
    float4* El = (float4*)Eld;
    #pragma unroll
    for (int j = 0; j < 8; ++j) El[tid + j * 256] = Eg[tid + j * 256];
  }
  const int l = tid & 63;
  const int wid = tid >> 6;
  const float* xb = x + (size_t)blockIdx.x * 128 * 512;

  // precompute per-j staging destinations (compile-time except tid)
  float4 rv[8];
  // preload tile 0
  #pragma unroll
  for (int j = 0; j < 8; ++j) {
    int idx = tid + j * 256;
    int row = idx >> 4;
    int c4 = (idx & 15) << 2;
    rv[j] = *(const float4*)(xb + (size_t)row * 512 + c4);
  }

  f32x16 acc = {0.f,0.f,0.f,0.f,0.f,0.f,0.f,0.f,0.f,0.f,0.f,0.f,0.f,0.f,0.f,0.f};

  for (int kt = 0; kt < 8; ++kt) {
    __syncthreads();  // previous compute done reading Th/Tl (also covers E stage)
    // convert current regs -> LDS fragments
    #pragma unroll
    for (int j = 0; j < 8; ++j) {
      int idx = tid + j * 256;
      int row = idx >> 4;
      int c4 = (idx & 15) << 2;      // 0..60, multiple of 4
      int w = row >> 5;
      int lane = (row & 31) + ((c4 >> 3) & 1) * 32;
      int s = c4 >> 4;
      int jj = c4 & 7;               // 0 or 4
      int off = (((w * 4 + s) * 64) + (lane ^ (s << 1))) * 8 + jj;
      float4 v = rv[j];
      unsigned u0 = __float_as_uint(v.x), u1 = __float_as_uint(v.y);
      unsigned u2 = __float_as_uint(v.z), u3 = __float_as_uint(v.w);
      float f0 = v.x - __uint_as_float(u0 & 0xFFFF0000u);
      float f1 = v.y - __uint_as_float(u1 & 0xFFFF0000u);
      float f2 = v.z - __uint_as_float(u2 & 0xFFFF0000u);
      float f3 = v.w - __uint_as_float(u3 & 0xFFFF0000u);
      unsigned h01 = (u1 & 0xFFFF0000u) | (u0 >> 16);
      unsigned h23 = (u3 & 0xFFFF0000u) | (u2 >> 16);
      unsigned l01 = (__float_as_uint(f1) & 0xFFFF0000u) | (__float_as_uint(f0) >> 16);
      unsigned l23 = (__float_as_uint(f3) & 0xFFFF0000u) | (__float_as_uint(f2) >> 16);
      *(uint2*)&Th[off] = make_uint2(h01, h23);
      *(uint2*)&Tl[off] = make_uint2(l01, l23);
    }
    // issue next tile's loads (fly under the MFMA phase)
    if (kt < 7) {
      #pragma unroll
      for (int j = 0; j < 8; ++j) {
        int idx = tid + j * 256;
        int row = idx >> 4;
        int c4 = (idx & 15) << 2;
        rv[j] = *(const float4*)(xb + (size_t)row * 512 + (kt + 1) * 64 + c4);
      }
    }
    __syncthreads();
    // compute: 4 k-steps of this tile
    #pragma unroll
    for (int s = 0; s < 4; ++s) {
      short8 hi = *(const short8*)&Th[(((wid * 4 + s) * 64) + (l ^ (s << 1))) * 8];
      short8 lo = *(const short8*)&Tl[(((wid * 4 + s) * 64) + (l ^ (s << 1))) * 8];
      short8 e  = *(const short8*)&Eld[(kt * 4 + s) * 512 + l * 8];
      acc = __builtin_amdgcn_mfma_f32_32x32x16_bf16(hi, e, acc, 0, 0, 0);
      acc = __builtin_amdgcn_mfma_f32_32x32x16_bf16(lo, e, acc, 0, 0, 0);
    }
  }

  // C layout: col = lane&31, row = (reg&3) + 8*(reg>>2) + 4*(lane>>5)
  const int col = l & 31;
  const int rq = (l >> 5) * 4;
  const int rb = blockIdx.x * 128 + wid * 32;
  #pragma unroll
  for (int r = 0; r < 16; ++r) {
    int rowt = (r & 3) + 8 * (r >> 2) + rq;
    A[(size_t)(rb + rowt) * 32 + col] = acc[r];
  }
}

// ---------------- Stage 2: DFT over h, 32 bins (ky 0..15, 496..511) ----
__global__ __launch_bounds__(512) void s2_kernel(const float* __restrict__ A,
                                                 float* __restrict__ F) {
  __shared__ float As[Hh * 32];   // 64 KB: full A image of one (b,i)
  __shared__ float ct[512];
  __shared__ float st[512];
  const int tid = threadIdx.x;
  const int bi = blockIdx.x;
  {
    float ang = TWO_PI * (float)tid / 512.0f;
    ct[tid] = cosf(ang);
    st[tid] = sinf(ang);
  }
  const float4* Ab = (const float4*)(A + (size_t)bi * (Hh * 32));
  float4* Asv = (float4*)As;
  #pragma unroll
  for (int j = 0; j < 8; ++j) Asv[tid + j * 512] = Ab[tid + j * 512];
  __syncthreads();
  const int kyp = tid >> 4;                       // 0..31
  const int kx = tid & 15;
  const int ky = (kyp < 16) ? kyp : (kyp + 480);  // 0..15 or 496..511
  float fr = 0.f, fi = 0.f;
  int t = 0;
  for (int h = 0; h < 512; ++h) {
    float2 a = *(const float2*)&As[h * 32 + kx * 2];
    float cc = ct[t], ss = st[t];
    // (ar + i ai) * (cc - i ss)
    fr = fmaf(a.x, cc, fr); fr = fmaf(a.y, ss, fr);
    fi = fmaf(a.y, cc, fi); fi = fmaf(-a.x, ss, fi);
    t = (t + ky) & 511;
  }
  size_t o = ((size_t)bi * KYp + kyp) * (HM * 2) + kx * 2;
  *(float2*)(F + o) = make_float2(fr, fi);
}

// ---------------- Stage 3: complex channel mix -------------------------
__global__ __launch_bounds__(512) void mix_kernel(const float* __restrict__ F,
    const float* __restrict__ w1r, const float* __restrict__ w1i,
    const float* __restrict__ w2r, const float* __restrict__ w2i,
    float* __restrict__ G) {
  const int tid = threadIdx.x;
  const int b = blockIdx.x >> 5;   // blockIdx = b*CO + o
  const int o = blockIdx.x & 31;
  const int kyp = tid >> 4;
  const int kx = tid & 15;
  const bool top = kyp < 16;
  const int m = top ? kyp : (kyp - 16);
  const float* wr = top ? w1r : w2r;
  const float* wi = top ? w1i : w2i;
  float gr = 0.f, gi = 0.f;
  for (int i = 0; i < CI; ++i) {
    float2 f = *(const float2*)&F[(((size_t)b * CI + i) * KYp + kyp) * (HM * 2) + kx * 2];
    size_t wo = (((size_t)i * CO + o) * HM + m) * HM + kx;
    float wrv = wr[wo], wiv = wi[wo];
    gr = fmaf(f.x, wrv, gr); gr = fmaf(-f.y, wiv, gr);
    gi = fmaf(f.x, wiv, gi); gi = fmaf(f.y, wrv, gi);
  }
  size_t go = ((size_t)blockIdx.x) * (KYp * HM * 2) + (kyp * HM + kx) * 2;
  *(float2*)(G + go) = make_float2(gr, gi);
}

// ---------------- Stage 4: inverse DFT over ky -> 512 rows -------------
__global__ __launch_bounds__(256) void t1_kernel(const float* __restrict__ G,
                                                 float* __restrict__ gws) {
  __shared__ float Gs[KYp * HM * 2];  // 4 KB
  __shared__ float ct[512];
  __shared__ float st[512];
  const int tid = threadIdx.x;
  const int blk = blockIdx.x;
  const int tile = blk & 31;
  const int bo = blk >> 5;
  #pragma unroll
  for (int j = 0; j < 2; ++j) {
    int t = tid + j * 256;
    float ang = TWO_PI * (float)t / 512.0f;
    ct[t] = cosf(ang);
    st[t] = sinf(ang);
  }
  ((float4*)Gs)[tid] = ((const float4*)(G + (size_t)bo * (KYp * HM * 2)))[tid];
  __syncthreads();
  const int r = tid >> 4;
  const int kx = tid & 15;
  const int h = tile * 16 + r;
  float gr = 0.f, gi = 0.f;
  #pragma unroll
  for (int kyp = 0; kyp < 32; ++kyp) {
    const int ky = (kyp < 16) ? kyp : (kyp + 480);
    const int t = (ky * h) & 511;
    float cc = ct[t], ss = st[t];
    float2 Gv = *(const float2*)&Gs[(kyp * HM + kx) * 2];
    // (Gr + i Gi) * (cc + i ss)
    gr = fmaf(Gv.x, cc, gr); gr = fmaf(-Gv.y, ss, gr);
    gi = fmaf(Gv.x, ss, gi); gi = fmaf(Gv.y, cc, gi);
  }
  size_t o = ((size_t)bo * Hh + h) * (HM * 2) + kx * 2;
  *(float2*)(gws + o) = make_float2(gr, gi);
}

// ---------------- Stage 5: inverse DFT over kx -> 512 cols, +bias ------
__global__ __launch_bounds__(256) void t2_kernel(const float* __restrict__ gws,
                                                 const float* __restrict__ bias,
                                                 float* __restrict__ y) {
  const int tid = threadIdx.x;
  const int blk = blockIdx.x;
  const int q = blk & 3;       // row quarter (128 rows)
  const int bo = blk >> 2;     // b*CO + o
  const int o = bo & 31;
  const float bv = bias[o];
  const float inv = 1.0f / 262144.0f;  // 1/(H*W)
  const int w0 = tid;          // columns w0 and w0+256
  float C[15], S[15];
  #pragma unroll
  for (int k = 0; k < 15; ++k) {
    int t = ((k + 1) * w0) & 511;
    float ang = TWO_PI * (float)t / 512.0f;
    float sv, cv;
    sincosf(ang, &sv, &cv);
    C[k] = 2.0f * cv;   // fold the hermitian x2 into the twiddle
    S[k] = 2.0f * sv;
  }
  const float* grow = gws + ((size_t)bo * Hh + q * 128) * (HM * 2);
  float* yrow = y + ((size_t)bo * Hh + q * 128) * Ww;
  for (int r = 0; r < 128; ++r) {
    float qa[32];
    const float4* gp = (const float4*)(grow + r * (HM * 2));
    #pragma unroll
    for (int j = 0; j < 8; ++j) ((float4*)qa)[j] = gp[j];
    // even/odd-k split: col w0 gets E+O, col w0+256 gets E-O (cos(th+k*pi))
    float E = qa[0];       // DC: real part only (pocketfft c2r semantics)
    float O = 0.f, E2 = 0.f, O2 = 0.f;
    #pragma unroll
    for (int k = 1; k <= 15; ++k) {
      float tv = fmaf(-qa[2 * k + 1], S[k - 1], qa[2 * k] * C[k - 1]);
      if (k & 1) { if (k & 2) O2 += tv; else O += tv; }
      else       { if (k & 2) E2 += tv; else E += tv; }
    }
    float Ee = E + E2, Oo = O + O2;
    yrow[r * Ww + w0]       = fmaf(inv, Ee + Oo, bv);
    yrow[r * Ww + w0 + 256] = fmaf(inv, Ee - Oo, bv);
  }
}

extern "C" void kernel_launch(void* const* d_in, const int* in_sizes, int n_in,
                              void* d_out, int out_size, void* d_ws, size_t ws_size,
                              hipStream_t stream) {
  const float* x    = (const float*)d_in[0];
  const float* w1r  = (const float*)d_in[1];
  const float* w1i  = (const float*)d_in[2];
  const float* w2r  = (const float*)d_in[3];
  const float* w2i  = (const float*)d_in[4];
  const float* bias = (const float*)d_in[5];
  float* y  = (float*)d_out;
  float* ws = (float*)d_ws;
  float* A  = ws + A_OFF;
  float* F  = ws + F_OFF;
  float* G  = ws + G_OFF;
  float* g  = ws + g_OFF;
  float* E  = ws + g_OFF;   // 32 KB, dead before t1 writes g

  hipLaunchKernelGGL(e_init_kernel, dim3(64),   dim3(256), 0, stream, E);
  hipLaunchKernelGGL(s1_kernel,  dim3(1024),    dim3(256), 0, stream, x, E, A);
  hipLaunchKernelGGL(s2_kernel,  dim3(Bb * CI), dim3(512), 0, stream, A, F);
  hipLaunchKernelGGL(mix_kernel, dim3(Bb * CO), dim3(512), 0, stream, F,
                     w1r, w1i, w2r, w2i, G);
  hipLaunchKernelGGL(t1_kernel,  dim3(Bb * CO * 32), dim3(256), 0, stream, G, g);
  hipLaunchKernelGGL(t2_kernel,  dim3(Bb * CO * 4),  dim3(256), 0, stream, g, bias, y);
}

// Round 4
// 199.490 us; speedup vs baseline: 1.5481x; 1.1432x over previous
//
#include <hip/hip_runtime.h>
#include <math.h>

#define Hh 512
#define Ww 512
#define Bb 8
#define CI 32
#define CO 32
#define HM 16   // kx modes kept
#define KYp 32  // packed ky modes (0..15 and 496..511)

static constexpr float TWO_PI = 6.28318530717958647692f;

// workspace layout (float offsets)
#define F_OFF  4194304u   // [B*CI][32][16][2] = 262,144 floats
#define G_OFF  4456448u   // [B*CO][32][16][2] = 262,144 floats
#define g_OFF  4718592u   // [B*CO][512][16][2] = 4,194,304 floats
// E  (bf16 phase-1 DFT frags, 32 KB)  at g_OFF          (dead before t1)
// E2c (bf16 phase-2 DFT frags, 64 KB) at g_OFF + 8192   (dead before t1)

using short8 = __attribute__((ext_vector_type(8))) short;
using f32x16 = __attribute__((ext_vector_type(16))) float;

__device__ inline unsigned short bf16_rn(float f) {
  unsigned u = __float_as_uint(f);
  u += 0x7FFFu + ((u >> 16) & 1u);
  return (unsigned short)(u >> 16);
}

// --------- E init: both DFT-matrix fragment tables -----------------------
// E   [kk(32)][lane][8]:  k = 16*kk... wait: k = kk*16 + 8*(l>>5)+j over w;
//     col = l&31 = 2*kx+c;  c==0: cos(2pi kx k/512), c==1: -sin
// E2c [mt(2)][kk(32)][lane][8]: rows kyc = l&31 = 2*kyp_loc+c over h;
//     h = kk*16+8*(l>>5)+j;  c==0: cos(2pi ky h/512), c==1: -sin
__global__ __launch_bounds__(256) void e_init_kernel(float* __restrict__ Ef) {
  unsigned short* E = (unsigned short*)Ef;
  int idx = blockIdx.x * 256 + threadIdx.x;   // 0..49151
  if (idx < 16384) {
    int kk = idx >> 9;
    int l = (idx >> 3) & 63;
    int j = idx & 7;
    int k = kk * 16 + 8 * (l >> 5) + j;
    int col = l & 31;
    int kx = col >> 1;
    int t = (kx * k) & 511;
    float sv, cv;
    sincosf(TWO_PI * (float)t / 512.0f, &sv, &cv);
    E[idx] = bf16_rn((col & 1) ? -sv : cv);
  } else {
    int idx2 = idx - 16384;
    int mt = idx2 >> 14;
    int rem = idx2 & 16383;
    int kk = rem >> 9;
    int l = (rem >> 3) & 63;
    int j = rem & 7;
    int h = kk * 16 + 8 * (l >> 5) + j;
    int kyc = l & 31;
    int kyp = mt * 16 + (kyc >> 1);
    int ky = (kyp < 16) ? kyp : (kyp + 480);
    int t = (ky * h) & 511;
    float sv, cv;
    sincosf(TWO_PI * (float)t / 512.0f, &sv, &cv);
    E[idx] = bf16_rn((kyc & 1) ? -sv : cv);
  }
}

// ---------------- fwd: x image -> F (fuses s1 + s2) ----------------------
// One block per (b,i). 512 thr = 8 waves. LDS 128 KB:
//   [0,32K)    E      (phase1) / E2c low half  (phase2)
//   [32K,64K)  Th|Tl  (phase1) / E2c high half (phase2)
//   [64K,96K)  Bfrag-hi (A as bf16) / Pbuf reduce (after barrier)
//   [96K,128K) Bfrag-lo
__global__ __launch_bounds__(512) void fwd_kernel(const float* __restrict__ x,
                                                  const float* __restrict__ Ef,
                                                  const float* __restrict__ E2f,
                                                  float* __restrict__ F) {
  __shared__ char lds[131072];
  short* Eld = (short*)lds;               // [kk(32)][64][8]
  short* Th  = (short*)(lds + 32768);     // [w(8)*2+s][64][8]
  short* Tl  = (short*)(lds + 49152);
  short* Bh  = (short*)(lds + 65536);     // [kk(32)][64][8]
  short* Bl  = (short*)(lds + 98304);
  short* E2l = (short*)lds;               // phase2: [mt(2)][kk(32)][64][8]
  float* Pbuf = (float*)(lds + 65536);    // phase2: [wid*4+r4][64] float4

  const int tid = threadIdx.x;
  const int l = tid & 63;
  const int wid = tid >> 6;
  const int bi = blockIdx.x;
  const float* xb = x + (size_t)bi * (Hh * Ww);

  // stage E (32 KB)
  {
    const float4* Eg = (const float4*)Ef;
    float4* El4 = (float4*)Eld;
    #pragma unroll
    for (int j = 0; j < 4; ++j) El4[tid + j * 512] = Eg[tid + j * 512];
  }

  // per-thread staging geometry (ktg-independent)
  const int srow = tid >> 3;              // 0..63  (+ j*64)
  const int c4 = (tid & 7) << 2;          // 0..28
  const int ss = c4 >> 4;                 // 0 or 1
  const int slanebit = (c4 >> 3) & 1;
  const int jj = c4 & 7;                  // 0 or 4

  float4 rvA[4], rvB[4];
  #define LOADRV(rv, ktg2) { \
    int ib2 = (ktg2) >> 4; int kt2 = (ktg2) & 15; \
    _Pragma("unroll") \
    for (int j = 0; j < 4; ++j) { \
      int row = ib2 * 256 + srow + j * 64; \
      rv[j] = *(const float4*)(xb + (size_t)row * 512 + kt2 * 32 + c4); \
    } }

  #define CONVSTORE(rv) { \
    _Pragma("unroll") \
    for (int j = 0; j < 4; ++j) { \
      int row = srow + j * 64; \
      int w = row >> 5; \
      int lane = (row & 31) + 32 * slanebit; \
      int offs = (((w * 2 + ss) * 64) + (lane ^ (ss << 1))) * 8 + jj; \
      float4 v = rv[j]; \
      unsigned u0 = __float_as_uint(v.x), u1 = __float_as_uint(v.y); \
      unsigned u2 = __float_as_uint(v.z), u3 = __float_as_uint(v.w); \
      float f0 = v.x - __uint_as_float(u0 & 0xFFFF0000u); \
      float f1 = v.y - __uint_as_float(u1 & 0xFFFF0000u); \
      float f2 = v.z - __uint_as_float(u2 & 0xFFFF0000u); \
      float f3 = v.w - __uint_as_float(u3 & 0xFFFF0000u); \
      unsigned h01 = (u1 & 0xFFFF0000u) | (u0 >> 16); \
      unsigned h23 = (u3 & 0xFFFF0000u) | (u2 >> 16); \
      unsigned l01 = (__float_as_uint(f1) & 0xFFFF0000u) | (__float_as_uint(f0) >> 16); \
      unsigned l23 = (__float_as_uint(f3) & 0xFFFF0000u) | (__float_as_uint(f2) >> 16); \
      *(uint2*)&Th[offs] = make_uint2(h01, h23); \
      *(uint2*)&Tl[offs] = make_uint2(l01, l23); \
    } }

  f32x16 acc = {0.f,0.f,0.f,0.f,0.f,0.f,0.f,0.f,0.f,0.f,0.f,0.f,0.f,0.f,0.f,0.f};

  #define MFMASTEP(ktg) { \
    int kt = (ktg) & 15; \
    _Pragma("unroll") \
    for (int s = 0; s < 2; ++s) { \
      short8 hi = *(const short8*)&Th[(((wid * 2 + s) * 64) + (l ^ (s << 1))) * 8]; \
      short8 lo = *(const short8*)&Tl[(((wid * 2 + s) * 64) + (l ^ (s << 1))) * 8]; \
      short8 e  = *(const short8*)&Eld[(kt * 2 + s) * 512 + l * 8]; \
      acc = __builtin_amdgcn_mfma_f32_32x32x16_bf16(hi, e, acc, 0, 0, 0); \
      acc = __builtin_amdgcn_mfma_f32_32x32x16_bf16(lo, e, acc, 0, 0, 0); \
    } }

  // flush acc (rows ib*256 + wid*32 ..+31) into Bfrag hi/lo, exact split
  #define FLUSHACC(ib) { \
    const int kx = l & 31; \
    _Pragma("unroll") \
    for (int q = 0; q < 4; ++q) { \
      int h0 = (ib) * 256 + wid * 32 + 8 * q + 4 * (l >> 5); \
      int kk_f = h0 >> 4; \
      int j0 = h0 & 7; \
      int offs = (kk_f * 64 + (kx + 32 * (q & 1))) * 8 + j0; \
      unsigned uh[4], ul[4]; \
      _Pragma("unroll") \
      for (int r = 0; r < 4; ++r) { \
        float a = acc[4 * q + r]; \
        unsigned u = __float_as_uint(a); \
        float fl = a - __uint_as_float(u & 0xFFFF0000u); \
        uh[r] = u >> 16; \
        ul[r] = __float_as_uint(fl) >> 16; \
      } \
      *(uint2*)&Bh[offs] = make_uint2((uh[1] << 16) | uh[0], (uh[3] << 16) | uh[2]); \
      *(uint2*)&Bl[offs] = make_uint2((ul[1] << 16) | ul[0], (ul[3] << 16) | ul[2]); \
    } }

  LOADRV(rvA, 0);
  LOADRV(rvB, 1);

  for (int ktg = 0; ktg < 32; ktg += 2) {
    __syncthreads();
    CONVSTORE(rvA);
    if (ktg + 2 < 32) LOADRV(rvA, ktg + 2);
    __syncthreads();
    MFMASTEP(ktg);

    __syncthreads();
    CONVSTORE(rvB);
    if (ktg + 3 < 32) LOADRV(rvB, ktg + 3);
    __syncthreads();
    MFMASTEP(ktg + 1);

    if ((ktg & 15) == 14) {
      int ib = ktg >> 4;
      FLUSHACC(ib);
      #pragma unroll
      for (int r = 0; r < 16; ++r) acc[r] = 0.f;
    }
  }

  __syncthreads();   // Bfrag complete; Eld/ThTl dead
  // stage E2c (64 KB) over [Eld|ThTl]
  {
    const float4* Eg = (const float4*)E2f;
    float4* El4 = (float4*)E2l;
    #pragma unroll
    for (int j = 0; j < 8; ++j) El4[tid + j * 512] = Eg[tid + j * 512];
  }
  __syncthreads();

  // phase 2: wave = (mt, part, kh); 16 MFMA over K-half
  {
    const int mt = wid & 1;
    const int part = (wid >> 1) & 1;
    const int kh = wid >> 2;
    const short* Bp = part ? Bl : Bh;
    f32x16 acc2 = {0.f,0.f,0.f,0.f,0.f,0.f,0.f,0.f,0.f,0.f,0.f,0.f,0.f,0.f,0.f,0.f};
    #pragma unroll
    for (int k2 = 0; k2 < 16; ++k2) {
      int kk = kh * 16 + k2;
      short8 af = *(const short8*)&E2l[(mt * 32 + kk) * 512 + l * 8];
      short8 bf = *(const short8*)&Bp[(kk * 64 + l) * 8];
      acc2 = __builtin_amdgcn_mfma_f32_32x32x16_bf16(af, bf, acc2, 0, 0, 0);
    }
    __syncthreads();   // all MFMAs done reading Bfrag
    #pragma unroll
    for (int r4 = 0; r4 < 4; ++r4) {
      *(float4*)&Pbuf[((wid * 4 + r4) * 64 + l) * 4] =
          make_float4(acc2[4*r4], acc2[4*r4+1], acc2[4*r4+2], acc2[4*r4+3]);
    }
  }
  __syncthreads();

  if (wid < 2) {
    const int mt = wid;
    float S[16];
    #pragma unroll
    for (int r = 0; r < 16; ++r) S[r] = 0.f;
    #pragma unroll
    for (int p = 0; p < 4; ++p) {
      #pragma unroll
      for (int r4 = 0; r4 < 4; ++r4) {
        float4 v = *(const float4*)&Pbuf[(((mt + 2 * p) * 4 + r4) * 64 + l) * 4];
        S[4*r4]   += v.x; S[4*r4+1] += v.y; S[4*r4+2] += v.z; S[4*r4+3] += v.w;
      }
    }
    // recombine complex: P = cos rows (even kyc), Q = -sin rows (odd kyc)
    const int c = l & 1;
    #pragma unroll
    for (int q = 0; q < 8; ++q) {
      int r0 = 2 * q;
      float T = __shfl_xor(S[r0 + 1], 1, 64);
      float val = c ? (S[r0] + T) : (S[r0] - T);
      int kyp_loc = ((r0 & 3) >> 1) + 4 * (r0 >> 2) + 2 * (l >> 5);
      F[((size_t)bi * 32 + mt * 16 + kyp_loc) * 32 + (l & 31)] = val;
    }
  }
}

// ---------------- Stage 3: complex channel mix -------------------------
__global__ __launch_bounds__(512) void mix_kernel(const float* __restrict__ F,
    const float* __restrict__ w1r, const float* __restrict__ w1i,
    const float* __restrict__ w2r, const float* __restrict__ w2i,
    float* __restrict__ G) {
  const int tid = threadIdx.x;
  const int b = blockIdx.x >> 5;   // blockIdx = b*CO + o
  const int o = blockIdx.x & 31;
  const int kyp = tid >> 4;
  const int kx = tid & 15;
  const bool top = kyp < 16;
  const int m = top ? kyp : (kyp - 16);
  const float* wr = top ? w1r : w2r;
  const float* wi = top ? w1i : w2i;
  float gr = 0.f, gi = 0.f;
  for (int i = 0; i < CI; ++i) {
    float2 f = *(const float2*)&F[(((size_t)b * CI + i) * KYp + kyp) * (HM * 2) + kx * 2];
    size_t wo = (((size_t)i * CO + o) * HM + m) * HM + kx;
    float wrv = wr[wo], wiv = wi[wo];
    gr = fmaf(f.x, wrv, gr); gr = fmaf(-f.y, wiv, gr);
    gi = fmaf(f.x, wiv, gi); gi = fmaf(f.y, wrv, gi);
  }
  size_t go = ((size_t)blockIdx.x) * (KYp * HM * 2) + (kyp * HM + kx) * 2;
  *(float2*)(G + go) = make_float2(gr, gi);
}

// ---------------- Stage 4: inverse DFT over ky -> 512 rows -------------
__global__ __launch_bounds__(256) void t1_kernel(const float* __restrict__ G,
                                                 float* __restrict__ gws) {
  __shared__ float Gs[KYp * HM * 2];  // 4 KB
  __shared__ float ct[512];
  __shared__ float st[512];
  const int tid = threadIdx.x;
  const int blk = blockIdx.x;
  const int tile = blk & 31;
  const int bo = blk >> 5;
  #pragma unroll
  for (int j = 0; j < 2; ++j) {
    int t = tid + j * 256;
    float ang = TWO_PI * (float)t / 512.0f;
    ct[t] = cosf(ang);
    st[t] = sinf(ang);
  }
  ((float4*)Gs)[tid] = ((const float4*)(G + (size_t)bo * (KYp * HM * 2)))[tid];
  __syncthreads();
  const int r = tid >> 4;
  const int kx = tid & 15;
  const int h = tile * 16 + r;
  float gr = 0.f, gi = 0.f;
  #pragma unroll
  for (int kyp = 0; kyp < 32; ++kyp) {
    const int ky = (kyp < 16) ? kyp : (kyp + 480);
    const int t = (ky * h) & 511;
    float cc = ct[t], ss = st[t];
    float2 Gv = *(const float2*)&Gs[(kyp * HM + kx) * 2];
    // (Gr + i Gi) * (cc + i ss)
    gr = fmaf(Gv.x, cc, gr); gr = fmaf(-Gv.y, ss, gr);
    gi = fmaf(Gv.x, ss, gi); gi = fmaf(Gv.y, cc, gi);
  }
  size_t o = ((size_t)bo * Hh + h) * (HM * 2) + kx * 2;
  *(float2*)(gws + o) = make_float2(gr, gi);
}

// ---------------- Stage 5: inverse DFT over kx -> 512 cols, +bias ------
__global__ __launch_bounds__(256) void t2_kernel(const float* __restrict__ gws,
                                                 const float* __restrict__ bias,
                                                 float* __restrict__ y) {
  const int tid = threadIdx.x;
  const int blk = blockIdx.x;
  const int q = blk & 3;       // row quarter (128 rows)
  const int bo = blk >> 2;     // b*CO + o
  const int o = bo & 31;
  const float bv = bias[o];
  const float inv = 1.0f / 262144.0f;  // 1/(H*W)
  const int w0 = tid;          // columns w0 and w0+256
  float C[15], S[15];
  #pragma unroll
  for (int k = 0; k < 15; ++k) {
    int t = ((k + 1) * w0) & 511;
    float ang = TWO_PI * (float)t / 512.0f;
    float sv, cv;
    sincosf(ang, &sv, &cv);
    C[k] = 2.0f * cv;   // fold the hermitian x2 into the twiddle
    S[k] = 2.0f * sv;
  }
  const float* grow = gws + ((size_t)bo * Hh + q * 128) * (HM * 2);
  float* yrow = y + ((size_t)bo * Hh + q * 128) * Ww;
  for (int r = 0; r < 128; ++r) {
    float qa[32];
    const float4* gp = (const float4*)(grow + r * (HM * 2));
    #pragma unroll
    for (int j = 0; j < 8; ++j) ((float4*)qa)[j] = gp[j];
    // even/odd-k split: col w0 gets E+O, col w0+256 gets E-O (cos(th+k*pi))
    float E = qa[0];       // DC: real part only (pocketfft c2r semantics)
    float O = 0.f, E2 = 0.f, O2 = 0.f;
    #pragma unroll
    for (int k = 1; k <= 15; ++k) {
      float tv = fmaf(-qa[2 * k + 1], S[k - 1], qa[2 * k] * C[k - 1]);
      if (k & 1) { if (k & 2) O2 += tv; else O += tv; }
      else       { if (k & 2) E2 += tv; else E += tv; }
    }
    float Ee = E + E2, Oo = O + O2;
    yrow[r * Ww + w0]       = fmaf(inv, Ee + Oo, bv);
    yrow[r * Ww + w0 + 256] = fmaf(inv, Ee - Oo, bv);
  }
}

extern "C" void kernel_launch(void* const* d_in, const int* in_sizes, int n_in,
                              void* d_out, int out_size, void* d_ws, size_t ws_size,
                              hipStream_t stream) {
  const float* x    = (const float*)d_in[0];
  const float* w1r  = (const float*)d_in[1];
  const float* w1i  = (const float*)d_in[2];
  const float* w2r  = (const float*)d_in[3];
  const float* w2i  = (const float*)d_in[4];
  const float* bias = (const float*)d_in[5];
  float* y  = (float*)d_out;
  float* ws = (float*)d_ws;
  float* F   = ws + F_OFF;
  float* G   = ws + G_OFF;
  float* g   = ws + g_OFF;
  float* E   = ws + g_OFF;          // 32 KB (dead before t1)
  float* E2c = ws + g_OFF + 8192;   // 64 KB (dead before t1)

  hipLaunchKernelGGL(e_init_kernel, dim3(192), dim3(256), 0, stream, E);
  hipLaunchKernelGGL(fwd_kernel,  dim3(Bb * CI), dim3(512), 0, stream, x, E, E2c, F);
  hipLaunchKernelGGL(mix_kernel, dim3(Bb * CO), dim3(512), 0, stream, F,
                     w1r, w1i, w2r, w2i, G);
  hipLaunchKernelGGL(t1_kernel,  dim3(Bb * CO * 32), dim3(256), 0, stream, G, g);
  hipLaunchKernelGGL(t2_kernel,  dim3(Bb * CO * 4),  dim3(256), 0, stream, g, bias, y);
}

// Round 5
// 195.703 us; speedup vs baseline: 1.5781x; 1.0194x over previous
//
#include <hip/hip_runtime.h>
#include <math.h>

#define Hh 512
#define Ww 512
#define Bb 8
#define CI 32
#define CO 32
#define HM 16   // kx modes kept
#define KYp 32  // packed ky modes (0..15 and 496..511)

static constexpr float TWO_PI = 6.28318530717958647692f;

// workspace layout (float offsets)
#define F_OFF  4194304u   // [B*CI][32][16][2] = 262,144 floats
#define G_OFF  4456448u   // [B*CO][32][16][2] = 262,144 floats
#define g_OFF  4718592u   // [B*CO][512][16][2] = 4,194,304 floats
// E  (bf16 phase-1 DFT frags, 32 KB)  at g_OFF          (dead before t1)
// E2c (bf16 phase-2 DFT frags, 64 KB) at g_OFF + 8192   (dead before t1)

using short8 = __attribute__((ext_vector_type(8))) short;
using f32x16 = __attribute__((ext_vector_type(16))) float;

__device__ inline unsigned short bf16_rn(float f) {
  unsigned u = __float_as_uint(f);
  u += 0x7FFFu + ((u >> 16) & 1u);
  return (unsigned short)(u >> 16);
}

// exact split of 4 floats into hi(bf16-trunc) + lo(residual as bf16)
__device__ inline void split4(float4 v, uint2& h2, uint2& l2) {
  unsigned u0 = __float_as_uint(v.x), u1 = __float_as_uint(v.y);
  unsigned u2 = __float_as_uint(v.z), u3 = __float_as_uint(v.w);
  float f0 = v.x - __uint_as_float(u0 & 0xFFFF0000u);
  float f1 = v.y - __uint_as_float(u1 & 0xFFFF0000u);
  float f2 = v.z - __uint_as_float(u2 & 0xFFFF0000u);
  float f3 = v.w - __uint_as_float(u3 & 0xFFFF0000u);
  h2.x = (u1 & 0xFFFF0000u) | (u0 >> 16);
  h2.y = (u3 & 0xFFFF0000u) | (u2 >> 16);
  l2.x = (__float_as_uint(f1) & 0xFFFF0000u) | (__float_as_uint(f0) >> 16);
  l2.y = (__float_as_uint(f3) & 0xFFFF0000u) | (__float_as_uint(f2) >> 16);
}

// --------- E init: both DFT-matrix fragment tables -----------------------
// E   [kk(32)][lane][8]: k = kk*16 + 8*(l>>5)+j over w; col = l&31 = 2kx+c
// E2c [mt(2)][kk(32)][lane][8]: kyc = l&31 = 2*kyp_loc+c; h = kk*16+8*(l>>5)+j
__global__ __launch_bounds__(256) void e_init_kernel(float* __restrict__ Ef) {
  unsigned short* E = (unsigned short*)Ef;
  int idx = blockIdx.x * 256 + threadIdx.x;   // 0..49151
  if (idx < 16384) {
    int kk = idx >> 9;
    int l = (idx >> 3) & 63;
    int j = idx & 7;
    int k = kk * 16 + 8 * (l >> 5) + j;
    int col = l & 31;
    int kx = col >> 1;
    int t = (kx * k) & 511;
    float sv, cv;
    sincosf(TWO_PI * (float)t / 512.0f, &sv, &cv);
    E[idx] = bf16_rn((col & 1) ? -sv : cv);
  } else {
    int idx2 = idx - 16384;
    int mt = idx2 >> 14;
    int rem = idx2 & 16383;
    int kk = rem >> 9;
    int l = (rem >> 3) & 63;
    int j = rem & 7;
    int h = kk * 16 + 8 * (l >> 5) + j;
    int kyc = l & 31;
    int kyp = mt * 16 + (kyc >> 1);
    int ky = (kyp < 16) ? kyp : (kyp + 480);
    int t = (ky * h) & 511;
    float sv, cv;
    sincosf(TWO_PI * (float)t / 512.0f, &sv, &cv);
    E[idx] = bf16_rn((kyc & 1) ? -sv : cv);
  }
}

// ---------------- fwd: x image -> F (row-contiguous HBM reads) -----------
// One block per (b,i), 512 thr = 8 waves, 1 block/CU (132 KB LDS).
// 16 steps of 32 contiguous rows: stage rows (1 KB-contiguous loads) ->
// LDS transpose to A-frags -> MFMA-1 (K split 8 ways over waves) ->
// LDS reduce -> 32 A-rows -> rank-32 phase-2 MFMA update (acc2).
__global__ __launch_bounds__(512) void fwd_kernel(const float* __restrict__ x,
                                                  const float* __restrict__ Ef,
                                                  const float* __restrict__ E2f,
                                                  float* __restrict__ F) {
  __shared__ char lds[135168];
  short* E2l = (short*)lds;                 // [mt 2][kk 32][64][8]  64 KB
  short* Xh  = (short*)(lds + 65536);       // [kc 32][64][8]        32 KB
  short* Xl  = (short*)(lds + 98304);       //                       32 KB
  float* red = (float*)(lds + 65536);       // alias Xh: [w8][q4][64][4] 32 KB
  short* Ah  = (short*)(lds + 131072);      // [kc2 2][64][8]         2 KB
  short* Al  = (short*)(lds + 133120);      //                        2 KB
  float* Pbuf = (float*)(lds + 65536);      // final reduce (alias)  32 KB

  const int tid = threadIdx.x;
  const int l = tid & 63;
  const int wid = tid >> 6;
  const int bi = blockIdx.x;
  const float* xb = x + (size_t)bi * (Hh * Ww);

  // stage E2c (64 KB), coalesced
  {
    const float4* Eg = (const float4*)E2f;
    float4* El4 = (float4*)E2l;
    #pragma unroll
    for (int j = 0; j < 8; ++j) El4[tid + j * 512] = Eg[tid + j * 512];
  }
  // E1 fragments for this wave's 4 w-chunks -> 16 VGPR
  short8 e1[4];
  {
    const short* Eg = (const short*)Ef;
    #pragma unroll
    for (int c = 0; c < 4; ++c)
      e1[c] = *(const short8*)(Eg + ((size_t)(4 * wid + c) * 64 + l) * 8);
  }

  // staging geometry: wave handles rows s*32 + wid*4 + j (j=0..3);
  // lane l covers cols 4l..4l+3 (first KB) and 256+4l.. (second KB)
  const int hb = (l >> 1) & 1;      // fragment lane-half from col group
  const int jfr = 4 * (l & 1);      // j' within fragment
  const int kc0 = l >> 2;           // w-chunk (first half)

  float4 rv[8];
  #pragma unroll
  for (int j = 0; j < 4; ++j) {
    const float* rowp = xb + (size_t)(wid * 4 + j) * 512;
    rv[2 * j]     = *(const float4*)(rowp + 4 * l);
    rv[2 * j + 1] = *(const float4*)(rowp + 256 + 4 * l);
  }

  f32x16 acc1 = {0.f,0.f,0.f,0.f,0.f,0.f,0.f,0.f,0.f,0.f,0.f,0.f,0.f,0.f,0.f,0.f};
  f32x16 acc2 = {0.f,0.f,0.f,0.f,0.f,0.f,0.f,0.f,0.f,0.f,0.f,0.f,0.f,0.f,0.f,0.f};

  const int mt2 = wid & 1, kc2w = (wid >> 1) & 1, part2 = wid >> 2;

  for (int s = 0; s < 16; ++s) {
    // ---- phase-2 MFMA for previous step (reads Ah/Al + E2l)
    if (s > 0) {
      short8 a2 = *(const short8*)&E2l[((mt2 * 32 + ((s - 1) * 2 + kc2w)) * 64 + l) * 8];
      short8 b2 = part2 ? *(const short8*)&Al[(kc2w * 64 + l) * 8]
                        : *(const short8*)&Ah[(kc2w * 64 + l) * 8];
      acc2 = __builtin_amdgcn_mfma_f32_32x32x16_bf16(a2, b2, acc2, 0, 0, 0);
    }
    // ---- scatter rv -> X fragments (XOR lane swizzle per chunk)
    #pragma unroll
    for (int j = 0; j < 4; ++j) {
      #pragma unroll
      for (int hf = 0; hf < 2; ++hf) {
        int kc = hf * 16 + kc0;
        int lanep = (wid * 4 + j) + 32 * hb;
        int off = ((kc * 64) + (lanep ^ (kc & 7))) * 8 + jfr;
        uint2 h2, l2;
        split4(rv[2 * j + hf], h2, l2);
        *(uint2*)&Xh[off] = h2;
        *(uint2*)&Xl[off] = l2;
      }
    }
    // ---- issue next step's loads (contiguous rows, fly under compute)
    if (s < 15) {
      #pragma unroll
      for (int j = 0; j < 4; ++j) {
        const float* rowp = xb + (size_t)((s + 1) * 32 + wid * 4 + j) * 512;
        rv[2 * j]     = *(const float4*)(rowp + 4 * l);
        rv[2 * j + 1] = *(const float4*)(rowp + 256 + 4 * l);
      }
    }
    __syncthreads();
    // ---- MFMA-1: this wave's 4 w-chunks, hi+lo
    #pragma unroll
    for (int c = 0; c < 4; ++c) {
      int kc = 4 * wid + c;
      int slot = ((kc * 64) + (l ^ (kc & 7))) * 8;
      short8 hi = *(const short8*)&Xh[slot];
      short8 lo = *(const short8*)&Xl[slot];
      acc1 = __builtin_amdgcn_mfma_f32_32x32x16_bf16(hi, e1[c], acc1, 0, 0, 0);
      acc1 = __builtin_amdgcn_mfma_f32_32x32x16_bf16(lo, e1[c], acc1, 0, 0, 0);
    }
    __syncthreads();
    // ---- write K-partials (X-frag region is dead now)
    #pragma unroll
    for (int q = 0; q < 4; ++q)
      *(float4*)&red[((wid * 4 + q) * 64 + l) * 4] =
          make_float4(acc1[4*q], acc1[4*q+1], acc1[4*q+2], acc1[4*q+3]);
    #pragma unroll
    for (int r = 0; r < 16; ++r) acc1[r] = 0.f;
    __syncthreads();
    // ---- reduce 8 partials -> 32 A-rows -> A fragments (hi/lo)
    if (wid < 4) {
      const int q = wid;
      float4 sum = make_float4(0.f, 0.f, 0.f, 0.f);
      #pragma unroll
      for (int w = 0; w < 8; ++w) {
        float4 v = *(const float4*)&red[((w * 4 + q) * 64 + l) * 4];
        sum.x += v.x; sum.y += v.y; sum.z += v.z; sum.w += v.w;
      }
      uint2 h2, l2;
      split4(sum, h2, l2);
      int off = ((q >> 1) * 64 + ((l & 31) + 32 * (q & 1))) * 8 + 4 * (l >> 5);
      *(uint2*)&Ah[off] = h2;
      *(uint2*)&Al[off] = l2;
    }
    __syncthreads();
  }
  // final phase-2 MFMA (s = 15)
  {
    short8 a2 = *(const short8*)&E2l[((mt2 * 32 + (15 * 2 + kc2w)) * 64 + l) * 8];
    short8 b2 = part2 ? *(const short8*)&Al[(kc2w * 64 + l) * 8]
                      : *(const short8*)&Ah[(kc2w * 64 + l) * 8];
    acc2 = __builtin_amdgcn_mfma_f32_32x32x16_bf16(a2, b2, acc2, 0, 0, 0);
  }
  // write acc2 partials -> Pbuf (region free since last reduce read)
  #pragma unroll
  for (int r4 = 0; r4 < 4; ++r4)
    *(float4*)&Pbuf[((wid * 4 + r4) * 64 + l) * 4] =
        make_float4(acc2[4*r4], acc2[4*r4+1], acc2[4*r4+2], acc2[4*r4+3]);
  __syncthreads();

  if (wid < 2) {
    const int mt = wid;
    float S[16];
    #pragma unroll
    for (int r = 0; r < 16; ++r) S[r] = 0.f;
    #pragma unroll
    for (int p = 0; p < 4; ++p) {
      #pragma unroll
      for (int r4 = 0; r4 < 4; ++r4) {
        float4 v = *(const float4*)&Pbuf[(((mt + 2 * p) * 4 + r4) * 64 + l) * 4];
        S[4*r4]   += v.x; S[4*r4+1] += v.y; S[4*r4+2] += v.z; S[4*r4+3] += v.w;
      }
    }
    // recombine complex: P = cos rows (even kyc), Q = -sin rows (odd kyc)
    const int c = l & 1;
    #pragma unroll
    for (int q = 0; q < 8; ++q) {
      int r0 = 2 * q;
      float T = __shfl_xor(S[r0 + 1], 1, 64);
      float val = c ? (S[r0] + T) : (S[r0] - T);
      int kyp_loc = ((r0 & 3) >> 1) + 4 * (r0 >> 2) + 2 * (l >> 5);
      F[((size_t)bi * 32 + mt * 16 + kyp_loc) * 32 + (l & 31)] = val;
    }
  }
}

// ---------------- Stage 3: complex channel mix -------------------------
__global__ __launch_bounds__(512) void mix_kernel(const float* __restrict__ F,
    const float* __restrict__ w1r, const float* __restrict__ w1i,
    const float* __restrict__ w2r, const float* __restrict__ w2i,
    float* __restrict__ G) {
  const int tid = threadIdx.x;
  const int b = blockIdx.x >> 5;   // blockIdx = b*CO + o
  const int o = blockIdx.x & 31;
  const int kyp = tid >> 4;
  const int kx = tid & 15;
  const bool top = kyp < 16;
  const int m = top ? kyp : (kyp - 16);
  const float* wr = top ? w1r : w2r;
  const float* wi = top ? w1i : w2i;
  float gr = 0.f, gi = 0.f;
  for (int i = 0; i < CI; ++i) {
    float2 f = *(const float2*)&F[(((size_t)b * CI + i) * KYp + kyp) * (HM * 2) + kx * 2];
    size_t wo = (((size_t)i * CO + o) * HM + m) * HM + kx;
    float wrv = wr[wo], wiv = wi[wo];
    gr = fmaf(f.x, wrv, gr); gr = fmaf(-f.y, wiv, gr);
    gi = fmaf(f.x, wiv, gi); gi = fmaf(f.y, wrv, gi);
  }
  size_t go = ((size_t)blockIdx.x) * (KYp * HM * 2) + (kyp * HM + kx) * 2;
  *(float2*)(G + go) = make_float2(gr, gi);
}

// ---------------- Stage 4: inverse DFT over ky -> 512 rows -------------
__global__ __launch_bounds__(256) void t1_kernel(const float* __restrict__ G,
                                                 float* __restrict__ gws) {
  __shared__ float Gs[KYp * HM * 2];  // 4 KB
  __shared__ float ct[512];
  __shared__ float st[512];
  const int tid = threadIdx.x;
  const int blk = blockIdx.x;
  const int tile = blk & 31;
  const int bo = blk >> 5;
  #pragma unroll
  for (int j = 0; j < 2; ++j) {
    int t = tid + j * 256;
    float ang = TWO_PI * (float)t / 512.0f;
    ct[t] = cosf(ang);
    st[t] = sinf(ang);
  }
  ((float4*)Gs)[tid] = ((const float4*)(G + (size_t)bo * (KYp * HM * 2)))[tid];
  __syncthreads();
  const int r = tid >> 4;
  const int kx = tid & 15;
  const int h = tile * 16 + r;
  float gr = 0.f, gi = 0.f;
  #pragma unroll
  for (int kyp = 0; kyp < 32; ++kyp) {
    const int ky = (kyp < 16) ? kyp : (kyp + 480);
    const int t = (ky * h) & 511;
    float cc = ct[t], ss = st[t];
    float2 Gv = *(const float2*)&Gs[(kyp * HM + kx) * 2];
    // (Gr + i Gi) * (cc + i ss)
    gr = fmaf(Gv.x, cc, gr); gr = fmaf(-Gv.y, ss, gr);
    gi = fmaf(Gv.x, ss, gi); gi = fmaf(Gv.y, cc, gi);
  }
  size_t o = ((size_t)bo * Hh + h) * (HM * 2) + kx * 2;
  *(float2*)(gws + o) = make_float2(gr, gi);
}

// ---------------- Stage 5: inverse DFT over kx -> 512 cols, +bias ------
__global__ __launch_bounds__(256) void t2_kernel(const float* __restrict__ gws,
                                                 const float* __restrict__ bias,
                                                 float* __restrict__ y) {
  const int tid = threadIdx.x;
  const int blk = blockIdx.x;
  const int q = blk & 3;       // row quarter (128 rows)
  const int bo = blk >> 2;     // b*CO + o
  const int o = bo & 31;
  const float bv = bias[o];
  const float inv = 1.0f / 262144.0f;  // 1/(H*W)
  const int w0 = tid;          // columns w0 and w0+256
  float C[15], S[15];
  #pragma unroll
  for (int k = 0; k < 15; ++k) {
    int t = ((k + 1) * w0) & 511;
    float ang = TWO_PI * (float)t / 512.0f;
    float sv, cv;
    sincosf(ang, &sv, &cv);
    C[k] = 2.0f * cv;   // fold the hermitian x2 into the twiddle
    S[k] = 2.0f * sv;
  }
  const float* grow = gws + ((size_t)bo * Hh + q * 128) * (HM * 2);
  float* yrow = y + ((size_t)bo * Hh + q * 128) * Ww;
  for (int r = 0; r < 128; ++r) {
    float qa[32];
    const float4* gp = (const float4*)(grow + r * (HM * 2));
    #pragma unroll
    for (int j = 0; j < 8; ++j) ((float4*)qa)[j] = gp[j];
    // even/odd-k split: col w0 gets E+O, col w0+256 gets E-O (cos(th+k*pi))
    float E = qa[0];       // DC: real part only (pocketfft c2r semantics)
    float O = 0.f, E2 = 0.f, O2 = 0.f;
    #pragma unroll
    for (int k = 1; k <= 15; ++k) {
      float tv = fmaf(-qa[2 * k + 1], S[k - 1], qa[2 * k] * C[k - 1]);
      if (k & 1) { if (k & 2) O2 += tv; else O += tv; }
      else       { if (k & 2) E2 += tv; else E += tv; }
    }
    float Ee = E + E2, Oo = O + O2;
    yrow[r * Ww + w0]       = fmaf(inv, Ee + Oo, bv);
    yrow[r * Ww + w0 + 256] = fmaf(inv, Ee - Oo, bv);
  }
}

extern "C" void kernel_launch(void* const* d_in, const int* in_sizes, int n_in,
                              void* d_out, int out_size, void* d_ws, size_t ws_size,
                              hipStream_t stream) {
  const float* x    = (const float*)d_in[0];
  const float* w1r  = (const float*)d_in[1];
  const float* w1i  = (const float*)d_in[2];
  const float* w2r  = (const float*)d_in[3];
  const float* w2i  = (const float*)d_in[4];
  const float* bias = (const float*)d_in[5];
  float* y  = (float*)d_out;
  float* ws = (float*)d_ws;
  float* F   = ws + F_OFF;
  float* G   = ws + G_OFF;
  float* g   = ws + g_OFF;
  float* E   = ws + g_OFF;          // 32 KB (dead before t1)
  float* E2c = ws + g_OFF + 8192;   // 64 KB (dead before t1)

  hipLaunchKernelGGL(e_init_kernel, dim3(192), dim3(256), 0, stream, E);
  hipLaunchKernelGGL(fwd_kernel,  dim3(Bb * CI), dim3(512), 0, stream, x, E, E2c, F);
  hipLaunchKernelGGL(mix_kernel, dim3(Bb * CO), dim3(512), 0, stream, F,
                     w1r, w1i, w2r, w2i, G);
  hipLaunchKernelGGL(t1_kernel,  dim3(Bb * CO * 32), dim3(256), 0, stream, G, g);
  hipLaunchKernelGGL(t2_kernel,  dim3(Bb * CO * 4),  dim3(256), 0, stream, g, bias, y);
}